// Round 1
// baseline (113.303 us; speedup 1.0000x reference)
//
#include <hip/hip_runtime.h>

#define SDIM 256
#define NSEQ 256
#define CDIM 32
#define CZ 128
#define IB 8
#define JB 4

typedef __bf16 bfx8 __attribute__((ext_vector_type(8)));
typedef float fx4 __attribute__((ext_vector_type(4)));
typedef unsigned short u16x4 __attribute__((ext_vector_type(4)));

__device__ __forceinline__ unsigned short f2bf(float f) {
  unsigned int u = __float_as_uint(f);
  u += 0x7fffu + ((u >> 16) & 1u);   // round-to-nearest-even
  return (unsigned short)(u >> 16);
}

__device__ __forceinline__ void gload16(const void* g, void* l) {
  __builtin_amdgcn_global_load_lds((const __attribute__((address_space(1))) unsigned int*)g,
                                   (__attribute__((address_space(3))) unsigned int*)l,
                                   16, 0, 0);
}

// ---------------- prep: LN + ab projection (-> bf16, transposed) + W_out -> bf16 (k reordered) ----------------
__global__ __launch_bounds__(256) void opm_prep(
    const float* __restrict__ m_si, const float* __restrict__ gamma, const float* __restrict__ beta,
    const float* __restrict__ Wab, const float* __restrict__ Wout,
    unsigned short* __restrict__ a_t, unsigned short* __restrict__ b_t,
    unsigned short* __restrict__ w2bf)
{
  const int b = blockIdx.x;
  const int t = threadIdx.x;
  if (b < SDIM) {
    __shared__ float wab[2 * CDIM * CDIM];   // 64x32
    __shared__ float gbuf[2 * CDIM];
    for (int k = t; k < 2 * CDIM * CDIM; k += 256) wab[k] = Wab[k];
    if (t < CDIM) { gbuf[t] = gamma[t]; gbuf[CDIM + t] = beta[t]; }
    __syncthreads();

    float x[CDIM];
    const float* src = m_si + (b * NSEQ + t) * CDIM;
#pragma unroll
    for (int c4 = 0; c4 < CDIM / 4; ++c4) {
      fx4 v = *(const fx4*)(src + c4 * 4);
      x[c4 * 4 + 0] = v[0]; x[c4 * 4 + 1] = v[1];
      x[c4 * 4 + 2] = v[2]; x[c4 * 4 + 3] = v[3];
    }
    float mu = 0.f;
#pragma unroll
    for (int c = 0; c < CDIM; ++c) mu += x[c];
    mu *= (1.f / CDIM);
    float var = 0.f;
#pragma unroll
    for (int c = 0; c < CDIM; ++c) { float d = x[c] - mu; var += d * d; }
    var *= (1.f / CDIM);
    const float inv = rsqrtf(var + 1e-5f);
#pragma unroll
    for (int c = 0; c < CDIM; ++c) x[c] = (x[c] - mu) * inv * gbuf[c] + gbuf[CDIM + c];

    for (int dp = 0; dp < 2 * CDIM; ++dp) {
      float s = 0.f;
#pragma unroll
      for (int c = 0; c < CDIM; ++c) s += x[c] * wab[dp * CDIM + c];
      const unsigned short hv = f2bf(s);
      if (dp < CDIM) a_t[(b * CDIM + dp) * NSEQ + t] = hv;
      else           b_t[(b * CDIM + (dp - CDIM)) * NSEQ + t] = hv;
    }
  } else {
    // W_out (z, c*32+d) -> bf16 (z, d*32+c)   [coalesced writes]
    const int idx = (b - SDIM) * 256 + t;      // 0..2047, 64 elems each
    const int flat = idx * 64;
    const int z = flat >> 10;
    const int k0 = flat & 1023;
#pragma unroll 8
    for (int u = 0; u < 64; ++u) {
      const int kp = k0 + u;
      const int d = kp >> 5, c = kp & 31;
      w2bf[flat + u] = f2bf(Wout[z * 1024 + c * CDIM + d]);
    }
  }
}

// ---------------- main: per-block 8x4 (i,j) pairs ----------------
// phase A: O[p][d][c] = sum_n a[i][n][c] * b[j][n][d] / 256   (bf16 in LDS, XOR-swizzled)
// phase B: z[i,j,z'] = sum_k' W2[z'][k'] * O[p][k'] + b_out   (k' = d*32+c)
__global__ __launch_bounds__(512) void opm_main(
    const unsigned short* __restrict__ a_t, const unsigned short* __restrict__ b_t,
    const unsigned short* __restrict__ w2, const float* __restrict__ bout,
    float* __restrict__ out)
{
  __shared__ __align__(16) char smem[65536];
  char* a_sh = smem;                  // 256 rows x 128B = 32768
  char* b_sh = smem + 32768;          // 128 rows x 128B = 16384
  char* o_sh = smem;                  // 32 pairs x 2048B = 65536 (union; used after phase A)

  const int tid = threadIdx.x;
  const int lane = tid & 63;
  const int wid = tid >> 6;           // 0..7
  const int g = lane >> 4;            // 0..3
  const int l15 = lane & 15;

  const int bx = blockIdx.x;
  const int i0 = (bx >> 6) * IB;      // 32 i-tiles
  const int j0 = (bx & 63) * JB;      // 64 j-tiles

  const int jw = wid >> 1;            // wave's j (0..3)
  const int mhalf = wid & 1;          // row half (0..1)

  fx4 acc[8][2] = {};

  for (int nc = 0; nc < 4; ++nc) {
    const int nbase = nc * 64;
    // stage a: 2048 x 16B chunks; source pre-swizzled so linear LDS + XOR read works
#pragma unroll
    for (int pass = 0; pass < 4; ++pass) {
      const int q0 = pass * 512 + wid * 64;
      const int q = q0 + lane;
      const int row = q >> 3;
      const int gs = (q & 7) ^ (row & 7);
      const unsigned short* src = a_t + (((i0 + (row >> 5)) * CDIM + (row & 31)) * NSEQ + nbase + gs * 8);
      gload16(src, a_sh + q0 * 16);
    }
    // stage b: 1024 x 16B chunks
#pragma unroll
    for (int pass = 0; pass < 2; ++pass) {
      const int q0 = pass * 512 + wid * 64;
      const int q = q0 + lane;
      const int row = q >> 3;
      const int gs = (q & 7) ^ (row & 7);
      const unsigned short* src = b_t + (((j0 + (row >> 5)) * CDIM + (row & 31)) * NSEQ + nbase + gs * 8);
      gload16(src, b_sh + q0 * 16);
    }
    asm volatile("s_waitcnt vmcnt(0)" ::: "memory");
    __syncthreads();

#pragma unroll
    for (int ks = 0; ks < 2; ++ks) {
      bfx8 bfrag[2];
#pragma unroll
      for (int nt = 0; nt < 2; ++nt) {
        const int rb = jw * 32 + nt * 16 + l15;
        const int gc = (ks * 4 + g) ^ (rb & 7);
        bfrag[nt] = *(const bfx8*)(b_sh + rb * 128 + gc * 16);
      }
#pragma unroll
      for (int mi = 0; mi < 8; ++mi) {
        const int rm = mhalf * 128 + mi * 16 + l15;
        const int gc = (ks * 4 + g) ^ (rm & 7);
        const bfx8 afrag = *(const bfx8*)(a_sh + rm * 128 + gc * 16);
#pragma unroll
        for (int nt = 0; nt < 2; ++nt)
          acc[mi][nt] = __builtin_amdgcn_mfma_f32_16x16x32_bf16(afrag, bfrag[nt], acc[mi][nt], 0, 0, 0);
      }
    }
    __syncthreads();   // readers done; safe to restage / write O
  }

  // O -> LDS, layout [p][d*64 + c*2] bytes, swizzle ^(((d^p)&7)<<4); scale 1/256
#pragma unroll
  for (int mi = 0; mi < 8; ++mi) {
    const int mt = mhalf * 8 + mi;
    const int p = (mt >> 1) * JB + jw;
    const int c0 = (mt & 1) * 16 + g * 4;
#pragma unroll
    for (int nt = 0; nt < 2; ++nt) {
      const int d = nt * 16 + l15;
      int inner = d * 64 + c0 * 2;
      inner ^= ((d ^ p) & 7) << 4;
      u16x4 v;
      v[0] = f2bf(acc[mi][nt][0] * 0.00390625f);
      v[1] = f2bf(acc[mi][nt][1] * 0.00390625f);
      v[2] = f2bf(acc[mi][nt][2] * 0.00390625f);
      v[3] = f2bf(acc[mi][nt][3] * 0.00390625f);
      *(u16x4*)(o_sh + p * 2048 + inner) = v;
    }
  }
  __syncthreads();

  // phase B: Z[z'][p] = sum_{k'} W2[z'][k'] O[p][k']
  {
    const int mt = wid;               // z' tile
    fx4 accB0 = {0.f, 0.f, 0.f, 0.f};
    fx4 accB1 = {0.f, 0.f, 0.f, 0.f};
    const unsigned short* wrow = w2 + (mt * 16 + l15) * 1024 + g * 8;
    const int pa = l15;
    const int pb = 16 + l15;
#pragma unroll 8
    for (int ks = 0; ks < 32; ++ks) {
      const bfx8 wf = *(const bfx8*)(wrow + ks * 32);
      const int base = ks * 64 + g * 16;
      const int ia = base ^ (((ks ^ pa) & 7) << 4);
      const int ib = base ^ (((ks ^ pb) & 7) << 4);
      const bfx8 oa = *(const bfx8*)(o_sh + pa * 2048 + ia);
      const bfx8 ob = *(const bfx8*)(o_sh + pb * 2048 + ib);
      accB0 = __builtin_amdgcn_mfma_f32_16x16x32_bf16(wf, oa, accB0, 0, 0, 0);
      accB1 = __builtin_amdgcn_mfma_f32_16x16x32_bf16(wf, ob, accB1, 0, 0, 0);
    }
    const int zp = mt * 16 + g * 4;
    const fx4 bo = *(const fx4*)(bout + zp);
    const fx4 v0 = accB0 + bo;
    const fx4 v1 = accB1 + bo;
    {
      int i = i0 + (pa >> 2), j = j0 + (pa & 3);
      *(fx4*)(out + ((i * SDIM + j) * CZ + zp)) = v0;
    }
    {
      int i = i0 + (pb >> 2), j = j0 + (pb & 3);
      *(fx4*)(out + ((i * SDIM + j) * CZ + zp)) = v1;
    }
  }
}

extern "C" void kernel_launch(void* const* d_in, const int* in_sizes, int n_in,
                              void* d_out, int out_size, void* d_ws, size_t ws_size,
                              hipStream_t stream) {
  const float* m_si  = (const float*)d_in[0];
  const float* gamma = (const float*)d_in[1];
  const float* beta  = (const float*)d_in[2];
  const float* Wab   = (const float*)d_in[3];
  const float* Wout  = (const float*)d_in[4];
  const float* bout  = (const float*)d_in[5];
  float* out = (float*)d_out;

  char* ws = (char*)d_ws;
  unsigned short* a_t = (unsigned short*)ws;                    // 4 MB
  unsigned short* b_t = (unsigned short*)(ws + (4u << 20));     // 4 MB
  unsigned short* w2  = (unsigned short*)(ws + (8u << 20));     // 256 KB

  opm_prep<<<dim3(SDIM + 8), dim3(256), 0, stream>>>(m_si, gamma, beta, Wab, Wout, a_t, b_t, w2);
  opm_main<<<dim3(2048), dim3(512), 0, stream>>>(a_t, b_t, w2, bout, out);
}